// Round 25
// baseline (560.699 us; speedup 1.0000x reference)
//
#include <hip/hip_runtime.h>
#include <hip/hip_fp16.h>

#define NN 100000
#define NE 1600000
#define HID 128
#define HEADS 4
#define CH 32
#define IN_DIM 257
#define CHK 64   // edges per LDS chunk in gather
#define KP1 288  // padded K for layer-1 wt16 (9 chunks of 32; zeros past 257)
#define KP2 128

typedef float f32x4 __attribute__((ext_vector_type(4)));
typedef _Float16 h8 __attribute__((ext_vector_type(8)));
typedef unsigned u4v __attribute__((ext_vector_type(4)));

__device__ __forceinline__ __half2 u2h2(unsigned u) {
    union { unsigned u; __half2 h; } cv;
    cv.u = u;
    return cv.h;
}

// ==================== MFMA projection + fused attention scalars ====================
template <bool XHALF>
__global__ __launch_bounds__(256, 4) void mfma_proj(const void* __restrict__ Xin,
                                                    const __half* __restrict__ wt16,
                                                    const float* __restrict__ att_src,
                                                    const float* __restrict__ att_dst,
                                                    __half* __restrict__ XSH,
                                                    float* __restrict__ asrc,
                                                    float* __restrict__ adst,
                                                    int K, int KP, long long maxx) {
    __shared__ __half xt[2][64][40];
    __shared__ __half wtile[2][128][40];
    int tid = threadIdx.x;
    int lane = tid & 63;
    int wv = tid >> 6;
    int block0 = blockIdx.x * 64;
    int nchunk = (K + 31) >> 5;

    int sn = tid >> 2;        // node 0..63
    int skb = (tid & 3) * 8;  // k sub-block
    int wn = tid >> 1;        // w row 0..127
    int woff = (tid & 1) * 16;

    f32x4 acc[8];
#pragma unroll
    for (int i = 0; i < 8; ++i) acc[i] = (f32x4){0.f, 0.f, 0.f, 0.f};

    float xr[8];
    uint4 xrh;
    uint4 wr0, wr1;

    auto loadX = [&](int k0) {
        if (XHALF) {
            const __half* Xh = (const __half*)Xin;
            long long a = (long long)(block0 + sn) * K + k0 + skb;
            if (a > maxx - 7) a = maxx - 7;
            xrh = *(const uint4*)&Xh[a];
        } else {
            const float* Xf = (const float*)Xin;
#pragma unroll
            for (int j = 0; j < 8; ++j) {
                long long a = (long long)(block0 + sn) * K + k0 + skb + j;
                if (a > maxx) a = maxx;
                xr[j] = Xf[a];
            }
        }
    };
    auto writeX = [&](int buf) {
        if (XHALF) {
            *(uint4*)&xt[buf][sn][skb] = xrh;
        } else {
            __half2 p0 = __floats2half2_rn(xr[0], xr[1]);
            __half2 p1 = __floats2half2_rn(xr[2], xr[3]);
            __half2 p2 = __floats2half2_rn(xr[4], xr[5]);
            __half2 p3 = __floats2half2_rn(xr[6], xr[7]);
            uint4 w;
            w.x = *(unsigned*)&p0; w.y = *(unsigned*)&p1;
            w.z = *(unsigned*)&p2; w.w = *(unsigned*)&p3;
            *(uint4*)&xt[buf][sn][skb] = w;
        }
    };
    auto loadW = [&](int k0) {
        const __half* src = &wt16[(long long)wn * KP + k0 + woff];
        wr0 = *(const uint4*)src;
        wr1 = *(const uint4*)(src + 8);
    };
    auto writeW = [&](int buf) {
        *(uint4*)&wtile[buf][wn][woff] = wr0;
        *(uint4*)&wtile[buf][wn][woff + 8] = wr1;
    };

    // prologue
    loadX(0);
    loadW(0);
    asm volatile("s_waitcnt vmcnt(0)" ::: "memory");
    writeX(0);
    writeW(0);
    __syncthreads();

    int m0 = wv * 16;
    int li = lane & 15;
    int kg = (lane >> 4) * 8;

    for (int c = 0; c < nchunk; ++c) {
        int cur = c & 1;
        bool more = (c + 1 < nchunk);
        if (more) { loadX((c + 1) * 32); loadW((c + 1) * 32); }
        uint4 av = *(const uint4*)&xt[cur][m0 + li][kg];
        h8 a = *(h8*)&av;
#pragma unroll
        for (int nt = 0; nt < 8; ++nt) {
            uint4 bv = *(const uint4*)&wtile[cur][nt * 16 + li][kg];
            h8 b = *(h8*)&bv;
            acc[nt] = __builtin_amdgcn_mfma_f32_16x16x32_f16(a, b, acc[nt], 0, 0, 0);
        }
        if (more) {
            asm volatile("s_waitcnt vmcnt(0)" ::: "memory");
            writeX(cur ^ 1);
            writeW(cur ^ 1);
        }
        __syncthreads();
    }

    // epilogue: lane holds D[node=(lane>>4)*4+r][col=nt*16+li] = acc[nt][r].
    float as_[8], ad_[8];
#pragma unroll
    for (int nt = 0; nt < 8; ++nt) {
        as_[nt] = att_src[nt * 16 + li];
        ad_[nt] = att_dst[nt * 16 + li];
    }
    int rbase = (lane >> 4) * 4;
#pragma unroll
    for (int r = 0; r < 4; ++r) {
        int node = block0 + m0 + rbase + r;
        bool ok = node < NN;
        if (ok) {
#pragma unroll
            for (int nt = 0; nt < 8; ++nt)
                XSH[(size_t)node * HID + nt * 16 + li] = __float2half(acc[nt][r]);
        }
#pragma unroll
        for (int h = 0; h < 4; ++h) {
            float s = acc[2 * h][r] * as_[2 * h] + acc[2 * h + 1][r] * as_[2 * h + 1];
            float d = acc[2 * h][r] * ad_[2 * h] + acc[2 * h + 1][r] * ad_[2 * h + 1];
            s += __shfl_xor(s, 1); d += __shfl_xor(d, 1);
            s += __shfl_xor(s, 2); d += __shfl_xor(d, 2);
            s += __shfl_xor(s, 4); d += __shfl_xor(d, 4);
            s += __shfl_xor(s, 8); d += __shfl_xor(d, 8);
            if (ok && li == 0) {
                asrc[node * 4 + h] = s;
                adst[node * 4 + h] = d;
            }
        }
    }
}

// ---- W prep: wt16[n][k] = fp16(W[k][n]), zero-padded past K ----
__global__ __launch_bounds__(256) void w_prep(const float* __restrict__ W1,
                                              const float* __restrict__ W2,
                                              __half* __restrict__ wt1,
                                              __half* __restrict__ wt2) {
    int i = blockIdx.x * 256 + threadIdx.x;
    const int tot1 = HID * KP1;
    const int tot2 = HID * KP2;
    if (i < tot1) {
        int n = i / KP1, k = i % KP1;
        wt1[i] = (k < IN_DIM) ? __float2half(W1[(size_t)k * HID + n]) : __float2half(0.f);
    } else if (i < tot1 + tot2) {
        int i2 = i - tot1;
        int n = i2 >> 7, k = i2 & 127;
        wt2[i2] = __float2half(W2[(size_t)k * HID + n]);
    }
}

// ---- ve[d,h] = sum_c We[d, h*CH+c] * att_edge[h,c]  (8x4), both layers at once ----
__global__ void compute_ve2(const float* __restrict__ We1,
                            const float* __restrict__ ae1,
                            const float* __restrict__ We2,
                            const float* __restrict__ ae2,
                            float* __restrict__ ve1,
                            float* __restrict__ ve2) {
    int i = threadIdx.x;
    if (i >= 64) return;
    const float* We = (i < 32) ? We1 : We2;
    const float* ae = (i < 32) ? ae1 : ae2;
    float* ve = (i < 32) ? ve1 : ve2;
    int j = i & 31;
    int d = j >> 2, h = j & 3;
    float s = 0.f;
    for (int c = 0; c < CH; ++c) s += We[d * HID + h * CH + c] * ae[h * CH + c];
    ve[j] = s;
}

// ==================== CSR build ====================
__global__ __launch_bounds__(256) void k_deg(const int* __restrict__ ei, int* __restrict__ deg) {
    int e = blockIdx.x * 256 + threadIdx.x;
    if (e < NE) atomicAdd(&deg[ei[NE + e]], 1);
}

__global__ __launch_bounds__(256) void scan_local(const int* __restrict__ deg,
                                                  int* __restrict__ startv,
                                                  int* __restrict__ bsum) {
    __shared__ int sh[256];
    int t = threadIdx.x;
    int base = blockIdx.x * 1024 + t * 4;
    int v0 = 0, v1 = 0, v2 = 0, v3 = 0;
    if (base + 0 < NN) v0 = deg[base + 0];
    if (base + 1 < NN) v1 = deg[base + 1];
    if (base + 2 < NN) v2 = deg[base + 2];
    if (base + 3 < NN) v3 = deg[base + 3];
    int s1 = v0 + v1, s2 = s1 + v2, s3 = s2 + v3;
    sh[t] = s3;
    __syncthreads();
    for (int off = 1; off < 256; off <<= 1) {
        int x = (t >= off) ? sh[t - off] : 0;
        __syncthreads();
        sh[t] += x;
        __syncthreads();
    }
    int thOff = sh[t] - s3;  // exclusive
    if (base + 0 < NN) startv[base + 0] = thOff;
    if (base + 1 < NN) startv[base + 1] = thOff + v0;
    if (base + 2 < NN) startv[base + 2] = thOff + s1;
    if (base + 3 < NN) startv[base + 3] = thOff + s2;
    if (t == 255) bsum[blockIdx.x] = sh[255];
}

__global__ __launch_bounds__(256) void scan_bsum(int* __restrict__ bsum, int nb) {
    __shared__ int sh[256];
    int t = threadIdx.x;
    int v = (t < nb) ? bsum[t] : 0;
    sh[t] = v;
    __syncthreads();
    for (int off = 1; off < 256; off <<= 1) {
        int x = (t >= off) ? sh[t - off] : 0;
        __syncthreads();
        sh[t] += x;
        __syncthreads();
    }
    if (t < nb) bsum[t] = sh[t] - v;  // exclusive
}

__global__ __launch_bounds__(256) void scan_add(int* __restrict__ startv,
                                                const int* __restrict__ bsum) {
    int i = blockIdx.x * 256 + threadIdx.x;
    if (i < NN) startv[i] += bsum[i >> 10];
}

// place: inv[pos] = e. inv is 6.4MB -> L2-resident, random RMW absorbed by L2.
__global__ __launch_bounds__(256) void k_place(const int* __restrict__ ei,
                                               const int* __restrict__ startv,
                                               int* __restrict__ cursor,
                                               int* __restrict__ inv) {
    int e = blockIdx.x * 256 + threadIdx.x;
    if (e >= NE) return;
    int d = ei[NE + e];
    int pos = startv[d] + atomicAdd(&cursor[d], 1);
    inv[pos] = e;
}

// build: position-sequential. Reads inv[p] (seq), gathers ei/eattr (random READS,
// L2/L3-served), writes rec[p] as full contiguous lines (no RMW).
__global__ __launch_bounds__(256) void rec_build(const int* __restrict__ inv,
                                                 const int* __restrict__ ei,
                                                 const float* __restrict__ eattr,
                                                 const float* __restrict__ ve1,
                                                 const float* __restrict__ ve2,
                                                 unsigned* __restrict__ rec) {
    __shared__ float v1[32], v2[32];
    if (threadIdx.x < 32) v1[threadIdx.x] = ve1[threadIdx.x];
    else if (threadIdx.x < 64) v2[threadIdx.x - 32] = ve2[threadIdx.x - 32];
    __syncthreads();
    int p = blockIdx.x * 256 + threadIdx.x;
    if (p >= NE) return;
    int e = inv[p];
    int src = ei[e];
    float4 e0 = *(const float4*)&eattr[(size_t)e * 8];
    float4 e1 = *(const float4*)&eattr[(size_t)e * 8 + 4];
    float eav[8] = {e0.x, e0.y, e0.z, e0.w, e1.x, e1.y, e1.z, e1.w};
    float a1[4], a2[4];
#pragma unroll
    for (int hh = 0; hh < 4; ++hh) {
        float s1 = 0.f, s2 = 0.f;
#pragma unroll
        for (int dd = 0; dd < 8; ++dd) {
            s1 += eav[dd] * v1[dd * 4 + hh];
            s2 += eav[dd] * v2[dd * 4 + hh];
        }
        a1[hh] = s1;
        a2[hh] = s2;
    }
    __half2 a1lo = __floats2half2_rn(a1[0], a1[1]);
    __half2 a1hi = __floats2half2_rn(a1[2], a1[3]);
    __half2 a2lo = __floats2half2_rn(a2[0], a2[1]);
    __half2 a2hi = __floats2half2_rn(a2[2], a2[3]);
    uint4 r0, r1;
    r0.x = (unsigned)src; r0.y = *(unsigned*)&a1lo; r0.z = *(unsigned*)&a1hi; r0.w = 0;
    r1.x = (unsigned)src; r1.y = *(unsigned*)&a2lo; r1.z = *(unsigned*)&a2hi; r1.w = 0;
    *(uint4*)&rec[(size_t)p * 8] = r0;
    *(uint4*)&rec[(size_t)p * 8 + 4] = r1;
}

// ==================== fused gather: softmax (no-max) + aggregate + bias + relu ====
__global__ __launch_bounds__(256) void gat_gather(const int* __restrict__ startv,
                                                  const int* __restrict__ deg,
                                                  const unsigned* __restrict__ recL,  // rec + layer*4
                                                  const float* __restrict__ asrc,
                                                  const float* __restrict__ adst,
                                                  const __half* __restrict__ XSH,
                                                  const float* __restrict__ bias,
                                                  __half* __restrict__ OUT) {
    __shared__ float s_p[4][CHK * 4];
    __shared__ int s_src[4][CHK];
    int w = threadIdx.x >> 6;
    int wid = blockIdx.x * 4 + w;
    if (wid >= NN) return;
    int lane = threadIdx.x & 63;
    int s0 = startv[wid];
    int dg = deg[wid];
    float4 ad4 = *(const float4*)&adst[wid * 4];
    int h = lane >> 4;
    int c0 = lane * 2;

    float denom = 0.f, acc0 = 0.f, acc1 = 0.f;

    for (int cb = 0; cb < dg; cb += CHK) {
        int cnt = min(CHK, dg - cb);
        // stage: one 16B record per edge (wave-synchronous)
        for (int i = lane; i < cnt; i += 64) {
            int pos = s0 + cb + i;
            u4v rv = __builtin_nontemporal_load((const u4v*)&recL[(size_t)pos * 8]);
            int s = (int)rv.x;
            s_src[w][i] = s;
            float2 ae01 = __half22float2(u2h2(rv.y));
            float2 ae23 = __half22float2(u2h2(rv.z));
            float4 as4 = *(const float4*)&asrc[s * 4];
            float a0 = as4.x + ad4.x + ae01.x;
            float a1 = as4.y + ad4.y + ae01.y;
            float a2 = as4.z + ad4.z + ae23.x;
            float a3 = as4.w + ad4.w + ae23.y;
            a0 = (a0 > 0.f) ? a0 : 0.2f * a0;
            a1 = (a1 > 0.f) ? a1 : 0.2f * a1;
            a2 = (a2 > 0.f) ? a2 : 0.2f * a2;
            a3 = (a3 > 0.f) ? a3 : 0.2f * a3;
            *(float4*)&s_p[w][i * 4] =
                make_float4(__expf(a0), __expf(a1), __expf(a2), __expf(a3));
        }
        // accumulate sweep, 8 XS gathers in flight
        int j = 0;
        for (; j + 7 < cnt; j += 8) {
            int sv[8];
            float pv[8];
            __half2 xv[8];
#pragma unroll
            for (int q = 0; q < 8; ++q) {
                sv[q] = s_src[w][j + q];
                pv[q] = s_p[w][(j + q) * 4 + h];
            }
#pragma unroll
            for (int q = 0; q < 8; ++q) xv[q] = *(const __half2*)&XSH[(size_t)sv[q] * HID + c0];
#pragma unroll
            for (int q = 0; q < 8; ++q) {
                float2 xf = __half22float2(xv[q]);
                denom += pv[q];
                acc0 += pv[q] * xf.x;
                acc1 += pv[q] * xf.y;
            }
        }
        for (; j < cnt; ++j) {
            int s = s_src[w][j];
            float p = s_p[w][j * 4 + h];
            float2 xf = __half22float2(*(const __half2*)&XSH[(size_t)s * HID + c0]);
            denom += p;
            acc0 += p * xf.x;
            acc1 += p * xf.y;
        }
    }
    float inv_ = 1.f / (denom + 1e-16f);
    float2 bv = *(const float2*)&bias[c0];
    float o0 = fmaxf(acc0 * inv_ + bv.x, 0.f);
    float o1 = fmaxf(acc1 * inv_ + bv.y, 0.f);
    *(__half2*)&OUT[(size_t)wid * HID + c0] = __floats2half2_rn(o0, o1);
}

// ==================== pooling (fp16 input); 128-node chunks -> 782 blocks ====
#define POOL_CHUNK 128
__global__ __launch_bounds__(256) void pool_kernel(const __half* __restrict__ H,
                                                   const int* __restrict__ batch,
                                                   float* __restrict__ pooled,
                                                   float* __restrict__ counts) {
    __shared__ float tab[64 * HID];
    __shared__ float cnt[64];
    int tid = threadIdx.x;
    int n0 = blockIdx.x * POOL_CHUNK;
    int nmax = min(POOL_CHUNK, NN - n0);
    for (int i = tid; i < 64 * HID; i += 256) tab[i] = 0.f;
    if (tid < 64) cnt[tid] = 0.f;
    __syncthreads();
    for (int i = tid; i < nmax * 64; i += 256) {
        int n = n0 + (i >> 6), c2 = (i & 63) * 2;
        int g = batch[n];
        float2 hv = __half22float2(*(const __half2*)&H[(size_t)n * HID + c2]);
        atomicAdd(&tab[g * HID + c2], hv.x);
        atomicAdd(&tab[g * HID + c2 + 1], hv.y);
    }
    for (int n = tid; n < nmax; n += 256) atomicAdd(&cnt[batch[n0 + n]], 1.f);
    __syncthreads();
    int gmin = batch[n0], gmax = batch[n0 + nmax - 1];
    int ng = gmax - gmin + 1;
    for (int i = tid; i < ng * HID; i += 256) {
        int g = gmin + (i >> 7), c = i & 127;
        atomicAdd(&pooled[g * HID + c], tab[g * HID + c]);
    }
    if (tid < ng) atomicAdd(&counts[gmin + tid], cnt[gmin + tid]);
}

// ==================== classifier ====================
__global__ __launch_bounds__(64) void classifier(const float* __restrict__ pooled,
                                                 const float* __restrict__ counts,
                                                 const float* __restrict__ Wc1,
                                                 const float* __restrict__ bc1,
                                                 const float* __restrict__ Wc2,
                                                 const float* __restrict__ bc2,
                                                 float* __restrict__ out) {
    __shared__ float pl[HID];
    __shared__ float z[64];
    int g = blockIdx.x, t = threadIdx.x;
    float inv = 1.f / fmaxf(counts[g], 1.f);
    pl[t] = pooled[g * HID + t] * inv;
    pl[t + 64] = pooled[g * HID + 64 + t] * inv;
    __syncthreads();
    float a = bc1[t];
    for (int k = 0; k < HID; ++k) a += pl[k] * Wc1[k * 64 + t];
    z[t] = fmaxf(a, 0.f);
    __syncthreads();
    if (t < 2) {
        float o = bc2[t];
        for (int j = 0; j < 64; ++j) o += z[j] * Wc2[j * 2 + t];
        out[g * 2 + t] = o;
    }
}

extern "C" void kernel_launch(void* const* d_in, const int* in_sizes, int n_in,
                              void* d_out, int out_size, void* d_ws, size_t ws_size,
                              hipStream_t stream) {
    const float* x = (const float*)d_in[0];
    const int* ei = (const int*)d_in[1];
    const float* eattr = (const float*)d_in[2];
    const int* batch = (const int*)d_in[3];
    const float* W1 = (const float*)d_in[4];
    const float* att_src1 = (const float*)d_in[5];
    const float* att_dst1 = (const float*)d_in[6];
    const float* We1 = (const float*)d_in[7];
    const float* att_edge1 = (const float*)d_in[8];
    const float* b1 = (const float*)d_in[9];
    const float* W2 = (const float*)d_in[10];
    const float* att_src2 = (const float*)d_in[11];
    const float* att_dst2 = (const float*)d_in[12];
    const float* We2 = (const float*)d_in[13];
    const float* att_edge2 = (const float*)d_in[14];
    const float* b2 = (const float*)d_in[15];
    const float* Wc1 = (const float*)d_in[16];
    const float* bc1 = (const float*)d_in[17];
    const float* Wc2 = (const float*)d_in[18];
    const float* bc2 = (const float*)d_in[19];
    float* out = (float*)d_out;

    // workspace layout (all segments 16B-aligned)
    __half* XSH = (__half*)d_ws;                     // [N,128] fp16 proj out
    __half* H16 = XSH + (size_t)NN * HID;            // [N,128] fp16 gather out
    float* asrc = (float*)(H16 + (size_t)NN * HID);  // [N,4]
    float* adst = asrc + (size_t)NN * 4;             // [N,4]
    float* ve1 = adst + (size_t)NN * 4;              // [32]
    float* ve2 = ve1 + 32;                           // [32]
    float* pooled = ve2 + 32;                        // [64,128]
    float* counts = pooled + 64 * HID;               // [64]
    unsigned* rec = (unsigned*)(counts + 64);        // [E,8] uints: 2x16B sub-records
    __half* wt1 = (__half*)(rec + (size_t)NE * 8);   // [128,KP1]
    __half* wt2 = wt1 + HID * KP1;                   // [128,KP2]
    int* deg = (int*)(wt2 + HID * KP2);              // [N]
    int* cursor = deg + NN;                          // [N]
    int* startv = cursor + NN;                       // [N]
    int* bsum = startv + NN;                         // [256]
    int* inv = bsum + 256;                           // [E]

    int gProj = (NN + 63) / 64;  // 1563
    int gE = (NE + 255) / 256;
    int gGat = (NN + 3) / 4;
    int nScanBlk = (NN + 1023) / 1024;  // 98
    int gWP = (HID * KP1 + HID * KP2 + 255) / 256;

    // ===== one-time prep =====
    hipMemsetAsync(deg, 0, (size_t)2 * NN * sizeof(int), stream);  // deg + cursor
    compute_ve2<<<1, 64, 0, stream>>>(We1, att_edge1, We2, att_edge2, ve1, ve2);
    w_prep<<<gWP, 256, 0, stream>>>(W1, W2, wt1, wt2);
    k_deg<<<gE, 256, 0, stream>>>(ei, deg);
    scan_local<<<nScanBlk, 256, 0, stream>>>(deg, startv, bsum);
    scan_bsum<<<1, 256, 0, stream>>>(bsum, nScanBlk);
    scan_add<<<(NN + 255) / 256, 256, 0, stream>>>(startv, bsum);
    k_place<<<gE, 256, 0, stream>>>(ei, startv, cursor, inv);
    rec_build<<<gE, 256, 0, stream>>>(inv, ei, eattr, ve1, ve2, rec);

    // ===== layer 1 =====
    mfma_proj<false><<<gProj, 256, 0, stream>>>(x, wt1, att_src1, att_dst1, XSH, asrc, adst,
                                                IN_DIM, KP1, (long long)NN * IN_DIM - 1);
    gat_gather<<<gGat, 256, 0, stream>>>(startv, deg, rec, asrc, adst,
                                         XSH, b1, H16);  // H16 = h1 (fp16)

    // ===== layer 2 =====
    mfma_proj<true><<<gProj, 256, 0, stream>>>(H16, wt2, att_src2, att_dst2, XSH, asrc, adst,
                                               HID, KP2, (long long)NN * HID - 1);
    gat_gather<<<gGat, 256, 0, stream>>>(startv, deg, rec + 4, asrc, adst,
                                         XSH, b2, H16);  // H16 = h2 (fp16)

    // ===== pool + classify =====
    hipMemsetAsync(pooled, 0, (64 * HID + 64) * sizeof(float), stream);
    pool_kernel<<<(NN + POOL_CHUNK - 1) / POOL_CHUNK, 256, 0, stream>>>(H16, batch, pooled, counts);
    classifier<<<64, 64, 0, stream>>>(pooled, counts, Wc1, bc1, Wc2, bc2, out);
}

// Round 26
// 496.496 us; speedup vs baseline: 1.1293x; 1.1293x over previous
//
#include <hip/hip_runtime.h>
#include <hip/hip_fp16.h>

#define NN 100000
#define NE 1600000
#define HID 128
#define HEADS 4
#define CH 32
#define IN_DIM 257
#define CHK 64   // edges per LDS chunk in gather
#define KP1 288  // padded K for layer-1 wt16 (9 chunks of 32; zeros past 257)
#define KP2 128

typedef float f32x4 __attribute__((ext_vector_type(4)));
typedef _Float16 h8 __attribute__((ext_vector_type(8)));
typedef unsigned u4v __attribute__((ext_vector_type(4)));

__device__ __forceinline__ __half2 u2h2(unsigned u) {
    union { unsigned u; __half2 h; } cv;
    cv.u = u;
    return cv.h;
}

// ==================== MFMA projection + fused attention scalars ====================
template <bool XHALF>
__global__ __launch_bounds__(256, 4) void mfma_proj(const void* __restrict__ Xin,
                                                    const __half* __restrict__ wt16,
                                                    const float* __restrict__ att_src,
                                                    const float* __restrict__ att_dst,
                                                    __half* __restrict__ XSH,
                                                    float* __restrict__ asrc,
                                                    float* __restrict__ adst,
                                                    int K, int KP, long long maxx) {
    __shared__ __half xt[2][64][40];
    __shared__ __half wtile[2][128][40];
    int tid = threadIdx.x;
    int lane = tid & 63;
    int wv = tid >> 6;
    int block0 = blockIdx.x * 64;
    int nchunk = (K + 31) >> 5;

    int sn = tid >> 2;        // node 0..63
    int skb = (tid & 3) * 8;  // k sub-block
    int wn = tid >> 1;        // w row 0..127
    int woff = (tid & 1) * 16;

    f32x4 acc[8];
#pragma unroll
    for (int i = 0; i < 8; ++i) acc[i] = (f32x4){0.f, 0.f, 0.f, 0.f};

    float xr[8];
    uint4 xrh;
    uint4 wr0, wr1;

    auto loadX = [&](int k0) {
        if (XHALF) {
            const __half* Xh = (const __half*)Xin;
            long long a = (long long)(block0 + sn) * K + k0 + skb;
            if (a > maxx - 7) a = maxx - 7;
            xrh = *(const uint4*)&Xh[a];
        } else {
            const float* Xf = (const float*)Xin;
#pragma unroll
            for (int j = 0; j < 8; ++j) {
                long long a = (long long)(block0 + sn) * K + k0 + skb + j;
                if (a > maxx) a = maxx;
                xr[j] = Xf[a];
            }
        }
    };
    auto writeX = [&](int buf) {
        if (XHALF) {
            *(uint4*)&xt[buf][sn][skb] = xrh;
        } else {
            __half2 p0 = __floats2half2_rn(xr[0], xr[1]);
            __half2 p1 = __floats2half2_rn(xr[2], xr[3]);
            __half2 p2 = __floats2half2_rn(xr[4], xr[5]);
            __half2 p3 = __floats2half2_rn(xr[6], xr[7]);
            uint4 w;
            w.x = *(unsigned*)&p0; w.y = *(unsigned*)&p1;
            w.z = *(unsigned*)&p2; w.w = *(unsigned*)&p3;
            *(uint4*)&xt[buf][sn][skb] = w;
        }
    };
    auto loadW = [&](int k0) {
        const __half* src = &wt16[(long long)wn * KP + k0 + woff];
        wr0 = *(const uint4*)src;
        wr1 = *(const uint4*)(src + 8);
    };
    auto writeW = [&](int buf) {
        *(uint4*)&wtile[buf][wn][woff] = wr0;
        *(uint4*)&wtile[buf][wn][woff + 8] = wr1;
    };

    // prologue
    loadX(0);
    loadW(0);
    asm volatile("s_waitcnt vmcnt(0)" ::: "memory");
    writeX(0);
    writeW(0);
    __syncthreads();

    int m0 = wv * 16;
    int li = lane & 15;
    int kg = (lane >> 4) * 8;

    for (int c = 0; c < nchunk; ++c) {
        int cur = c & 1;
        bool more = (c + 1 < nchunk);
        if (more) { loadX((c + 1) * 32); loadW((c + 1) * 32); }
        uint4 av = *(const uint4*)&xt[cur][m0 + li][kg];
        h8 a = *(h8*)&av;
#pragma unroll
        for (int nt = 0; nt < 8; ++nt) {
            uint4 bv = *(const uint4*)&wtile[cur][nt * 16 + li][kg];
            h8 b = *(h8*)&bv;
            acc[nt] = __builtin_amdgcn_mfma_f32_16x16x32_f16(a, b, acc[nt], 0, 0, 0);
        }
        if (more) {
            asm volatile("s_waitcnt vmcnt(0)" ::: "memory");
            writeX(cur ^ 1);
            writeW(cur ^ 1);
        }
        __syncthreads();
    }

    // epilogue: lane holds D[node=(lane>>4)*4+r][col=nt*16+li] = acc[nt][r].
    float as_[8], ad_[8];
#pragma unroll
    for (int nt = 0; nt < 8; ++nt) {
        as_[nt] = att_src[nt * 16 + li];
        ad_[nt] = att_dst[nt * 16 + li];
    }
    int rbase = (lane >> 4) * 4;
#pragma unroll
    for (int r = 0; r < 4; ++r) {
        int node = block0 + m0 + rbase + r;
        bool ok = node < NN;
        if (ok) {
#pragma unroll
            for (int nt = 0; nt < 8; ++nt)
                XSH[(size_t)node * HID + nt * 16 + li] = __float2half(acc[nt][r]);
        }
#pragma unroll
        for (int h = 0; h < 4; ++h) {
            float s = acc[2 * h][r] * as_[2 * h] + acc[2 * h + 1][r] * as_[2 * h + 1];
            float d = acc[2 * h][r] * ad_[2 * h] + acc[2 * h + 1][r] * ad_[2 * h + 1];
            s += __shfl_xor(s, 1); d += __shfl_xor(d, 1);
            s += __shfl_xor(s, 2); d += __shfl_xor(d, 2);
            s += __shfl_xor(s, 4); d += __shfl_xor(d, 4);
            s += __shfl_xor(s, 8); d += __shfl_xor(d, 8);
            if (ok && li == 0) {
                asrc[node * 4 + h] = s;
                adst[node * 4 + h] = d;
            }
        }
    }
}

// ---- W prep: wt16[n][k] = fp16(W[k][n]), zero-padded past K ----
__global__ __launch_bounds__(256) void w_prep(const float* __restrict__ W1,
                                              const float* __restrict__ W2,
                                              __half* __restrict__ wt1,
                                              __half* __restrict__ wt2) {
    int i = blockIdx.x * 256 + threadIdx.x;
    const int tot1 = HID * KP1;
    const int tot2 = HID * KP2;
    if (i < tot1) {
        int n = i / KP1, k = i % KP1;
        wt1[i] = (k < IN_DIM) ? __float2half(W1[(size_t)k * HID + n]) : __float2half(0.f);
    } else if (i < tot1 + tot2) {
        int i2 = i - tot1;
        int n = i2 >> 7, k = i2 & 127;
        wt2[i2] = __float2half(W2[(size_t)k * HID + n]);
    }
}

// ---- ve[d,h] = sum_c We[d, h*CH+c] * att_edge[h,c]  (8x4), both layers at once ----
__global__ void compute_ve2(const float* __restrict__ We1,
                            const float* __restrict__ ae1,
                            const float* __restrict__ We2,
                            const float* __restrict__ ae2,
                            float* __restrict__ ve1,
                            float* __restrict__ ve2) {
    int i = threadIdx.x;
    if (i >= 64) return;
    const float* We = (i < 32) ? We1 : We2;
    const float* ae = (i < 32) ? ae1 : ae2;
    float* ve = (i < 32) ? ve1 : ve2;
    int j = i & 31;
    int d = j >> 2, h = j & 3;
    float s = 0.f;
    for (int c = 0; c < CH; ++c) s += We[d * HID + h * CH + c] * ae[h * CH + c];
    ve[j] = s;
}

// ==================== CSR build ====================
__global__ __launch_bounds__(256) void k_deg(const int* __restrict__ ei, int* __restrict__ deg) {
    int e = blockIdx.x * 256 + threadIdx.x;
    if (e < NE) atomicAdd(&deg[ei[NE + e]], 1);
}

__global__ __launch_bounds__(256) void scan_local(const int* __restrict__ deg,
                                                  int* __restrict__ startv,
                                                  int* __restrict__ bsum) {
    __shared__ int sh[256];
    int t = threadIdx.x;
    int base = blockIdx.x * 1024 + t * 4;
    int v0 = 0, v1 = 0, v2 = 0, v3 = 0;
    if (base + 0 < NN) v0 = deg[base + 0];
    if (base + 1 < NN) v1 = deg[base + 1];
    if (base + 2 < NN) v2 = deg[base + 2];
    if (base + 3 < NN) v3 = deg[base + 3];
    int s1 = v0 + v1, s2 = s1 + v2, s3 = s2 + v3;
    sh[t] = s3;
    __syncthreads();
    for (int off = 1; off < 256; off <<= 1) {
        int x = (t >= off) ? sh[t - off] : 0;
        __syncthreads();
        sh[t] += x;
        __syncthreads();
    }
    int thOff = sh[t] - s3;  // exclusive
    if (base + 0 < NN) startv[base + 0] = thOff;
    if (base + 1 < NN) startv[base + 1] = thOff + v0;
    if (base + 2 < NN) startv[base + 2] = thOff + s1;
    if (base + 3 < NN) startv[base + 3] = thOff + s2;
    if (t == 255) bsum[blockIdx.x] = sh[255];
}

__global__ __launch_bounds__(256) void scan_bsum(int* __restrict__ bsum, int nb) {
    __shared__ int sh[256];
    int t = threadIdx.x;
    int v = (t < nb) ? bsum[t] : 0;
    sh[t] = v;
    __syncthreads();
    for (int off = 1; off < 256; off <<= 1) {
        int x = (t >= off) ? sh[t - off] : 0;
        __syncthreads();
        sh[t] += x;
        __syncthreads();
    }
    if (t < nb) bsum[t] = sh[t] - v;  // exclusive
}

__global__ __launch_bounds__(256) void scan_add(int* __restrict__ startv,
                                                const int* __restrict__ bsum) {
    int i = blockIdx.x * 256 + threadIdx.x;
    if (i < NN) startv[i] += bsum[i >> 10];
}

// scatter: per edge, ONE 32B record = two self-contained 16B sub-records
// {src, ae_fp16[4], pad} (one per layer) -> single random line touch per edge.
__global__ __launch_bounds__(256) void k_scatter(const int* __restrict__ ei,
                                                 const int* __restrict__ startv,
                                                 int* __restrict__ cursor,
                                                 const float* __restrict__ eattr,
                                                 const float* __restrict__ ve1,
                                                 const float* __restrict__ ve2,
                                                 unsigned* __restrict__ rec) {
    __shared__ float v1[32], v2[32];
    if (threadIdx.x < 32) v1[threadIdx.x] = ve1[threadIdx.x];
    else if (threadIdx.x < 64) v2[threadIdx.x - 32] = ve2[threadIdx.x - 32];
    __syncthreads();
    int e = blockIdx.x * 256 + threadIdx.x;
    if (e >= NE) return;
    int d = ei[NE + e];
    int src = ei[e];
    float4 e0 = *(const float4*)&eattr[(size_t)e * 8];
    float4 e1 = *(const float4*)&eattr[(size_t)e * 8 + 4];
    float eav[8] = {e0.x, e0.y, e0.z, e0.w, e1.x, e1.y, e1.z, e1.w};
    float a1[4], a2[4];
#pragma unroll
    for (int hh = 0; hh < 4; ++hh) {
        float s1 = 0.f, s2 = 0.f;
#pragma unroll
        for (int dd = 0; dd < 8; ++dd) {
            s1 += eav[dd] * v1[dd * 4 + hh];
            s2 += eav[dd] * v2[dd * 4 + hh];
        }
        a1[hh] = s1;
        a2[hh] = s2;
    }
    __half2 a1lo = __floats2half2_rn(a1[0], a1[1]);
    __half2 a1hi = __floats2half2_rn(a1[2], a1[3]);
    __half2 a2lo = __floats2half2_rn(a2[0], a2[1]);
    __half2 a2hi = __floats2half2_rn(a2[2], a2[3]);
    int pos = startv[d] + atomicAdd(&cursor[d], 1);
    uint4 r0, r1;
    r0.x = (unsigned)src; r0.y = *(unsigned*)&a1lo; r0.z = *(unsigned*)&a1hi; r0.w = 0;
    r1.x = (unsigned)src; r1.y = *(unsigned*)&a2lo; r1.z = *(unsigned*)&a2hi; r1.w = 0;
    *(uint4*)&rec[(size_t)pos * 8] = r0;
    *(uint4*)&rec[(size_t)pos * 8 + 4] = r1;
}

// ==================== fused gather: softmax (no-max) + aggregate + bias + relu ====
__global__ __launch_bounds__(256) void gat_gather(const int* __restrict__ startv,
                                                  const int* __restrict__ deg,
                                                  const unsigned* __restrict__ recL,  // rec + layer*4
                                                  const float* __restrict__ asrc,
                                                  const float* __restrict__ adst,
                                                  const __half* __restrict__ XSH,
                                                  const float* __restrict__ bias,
                                                  __half* __restrict__ OUT) {
    __shared__ float s_p[4][CHK * 4];
    __shared__ int s_src[4][CHK];
    int w = threadIdx.x >> 6;
    int wid = blockIdx.x * 4 + w;
    if (wid >= NN) return;
    int lane = threadIdx.x & 63;
    int s0 = startv[wid];
    int dg = deg[wid];
    float4 ad4 = *(const float4*)&adst[wid * 4];
    int h = lane >> 4;
    int c0 = lane * 2;

    float denom = 0.f, acc0 = 0.f, acc1 = 0.f;

    for (int cb = 0; cb < dg; cb += CHK) {
        int cnt = min(CHK, dg - cb);
        // stage: one 16B record per edge (wave-synchronous)
        for (int i = lane; i < cnt; i += 64) {
            int pos = s0 + cb + i;
            u4v rv = __builtin_nontemporal_load((const u4v*)&recL[(size_t)pos * 8]);
            int s = (int)rv.x;
            s_src[w][i] = s;
            float2 ae01 = __half22float2(u2h2(rv.y));
            float2 ae23 = __half22float2(u2h2(rv.z));
            float4 as4 = *(const float4*)&asrc[s * 4];
            float a0 = as4.x + ad4.x + ae01.x;
            float a1 = as4.y + ad4.y + ae01.y;
            float a2 = as4.z + ad4.z + ae23.x;
            float a3 = as4.w + ad4.w + ae23.y;
            a0 = (a0 > 0.f) ? a0 : 0.2f * a0;
            a1 = (a1 > 0.f) ? a1 : 0.2f * a1;
            a2 = (a2 > 0.f) ? a2 : 0.2f * a2;
            a3 = (a3 > 0.f) ? a3 : 0.2f * a3;
            *(float4*)&s_p[w][i * 4] =
                make_float4(__expf(a0), __expf(a1), __expf(a2), __expf(a3));
        }
        // accumulate sweep, 8 XS gathers in flight
        int j = 0;
        for (; j + 7 < cnt; j += 8) {
            int sv[8];
            float pv[8];
            __half2 xv[8];
#pragma unroll
            for (int q = 0; q < 8; ++q) {
                sv[q] = s_src[w][j + q];
                pv[q] = s_p[w][(j + q) * 4 + h];
            }
#pragma unroll
            for (int q = 0; q < 8; ++q) xv[q] = *(const __half2*)&XSH[(size_t)sv[q] * HID + c0];
#pragma unroll
            for (int q = 0; q < 8; ++q) {
                float2 xf = __half22float2(xv[q]);
                denom += pv[q];
                acc0 += pv[q] * xf.x;
                acc1 += pv[q] * xf.y;
            }
        }
        for (; j < cnt; ++j) {
            int s = s_src[w][j];
            float p = s_p[w][j * 4 + h];
            float2 xf = __half22float2(*(const __half2*)&XSH[(size_t)s * HID + c0]);
            denom += p;
            acc0 += p * xf.x;
            acc1 += p * xf.y;
        }
    }
    float inv_ = 1.f / (denom + 1e-16f);
    float2 bv = *(const float2*)&bias[c0];
    float o0 = fmaxf(acc0 * inv_ + bv.x, 0.f);
    float o1 = fmaxf(acc1 * inv_ + bv.y, 0.f);
    *(__half2*)&OUT[(size_t)wid * HID + c0] = __floats2half2_rn(o0, o1);
}

// ==================== pooling (fp16 input); 128-node chunks -> 782 blocks ====
#define POOL_CHUNK 128
__global__ __launch_bounds__(256) void pool_kernel(const __half* __restrict__ H,
                                                   const int* __restrict__ batch,
                                                   float* __restrict__ pooled,
                                                   float* __restrict__ counts) {
    __shared__ float tab[64 * HID];
    __shared__ float cnt[64];
    int tid = threadIdx.x;
    int n0 = blockIdx.x * POOL_CHUNK;
    int nmax = min(POOL_CHUNK, NN - n0);
    for (int i = tid; i < 64 * HID; i += 256) tab[i] = 0.f;
    if (tid < 64) cnt[tid] = 0.f;
    __syncthreads();
    for (int i = tid; i < nmax * 64; i += 256) {
        int n = n0 + (i >> 6), c2 = (i & 63) * 2;
        int g = batch[n];
        float2 hv = __half22float2(*(const __half2*)&H[(size_t)n * HID + c2]);
        atomicAdd(&tab[g * HID + c2], hv.x);
        atomicAdd(&tab[g * HID + c2 + 1], hv.y);
    }
    for (int n = tid; n < nmax; n += 256) atomicAdd(&cnt[batch[n0 + n]], 1.f);
    __syncthreads();
    int gmin = batch[n0], gmax = batch[n0 + nmax - 1];
    int ng = gmax - gmin + 1;
    for (int i = tid; i < ng * HID; i += 256) {
        int g = gmin + (i >> 7), c = i & 127;
        atomicAdd(&pooled[g * HID + c], tab[g * HID + c]);
    }
    if (tid < ng) atomicAdd(&counts[gmin + tid], cnt[gmin + tid]);
}

// ==================== classifier ====================
__global__ __launch_bounds__(64) void classifier(const float* __restrict__ pooled,
                                                 const float* __restrict__ counts,
                                                 const float* __restrict__ Wc1,
                                                 const float* __restrict__ bc1,
                                                 const float* __restrict__ Wc2,
                                                 const float* __restrict__ bc2,
                                                 float* __restrict__ out) {
    __shared__ float pl[HID];
    __shared__ float z[64];
    int g = blockIdx.x, t = threadIdx.x;
    float inv = 1.f / fmaxf(counts[g], 1.f);
    pl[t] = pooled[g * HID + t] * inv;
    pl[t + 64] = pooled[g * HID + 64 + t] * inv;
    __syncthreads();
    float a = bc1[t];
    for (int k = 0; k < HID; ++k) a += pl[k] * Wc1[k * 64 + t];
    z[t] = fmaxf(a, 0.f);
    __syncthreads();
    if (t < 2) {
        float o = bc2[t];
        for (int j = 0; j < 64; ++j) o += z[j] * Wc2[j * 2 + t];
        out[g * 2 + t] = o;
    }
}

extern "C" void kernel_launch(void* const* d_in, const int* in_sizes, int n_in,
                              void* d_out, int out_size, void* d_ws, size_t ws_size,
                              hipStream_t stream) {
    const float* x = (const float*)d_in[0];
    const int* ei = (const int*)d_in[1];
    const float* eattr = (const float*)d_in[2];
    const int* batch = (const int*)d_in[3];
    const float* W1 = (const float*)d_in[4];
    const float* att_src1 = (const float*)d_in[5];
    const float* att_dst1 = (const float*)d_in[6];
    const float* We1 = (const float*)d_in[7];
    const float* att_edge1 = (const float*)d_in[8];
    const float* b1 = (const float*)d_in[9];
    const float* W2 = (const float*)d_in[10];
    const float* att_src2 = (const float*)d_in[11];
    const float* att_dst2 = (const float*)d_in[12];
    const float* We2 = (const float*)d_in[13];
    const float* att_edge2 = (const float*)d_in[14];
    const float* b2 = (const float*)d_in[15];
    const float* Wc1 = (const float*)d_in[16];
    const float* bc1 = (const float*)d_in[17];
    const float* Wc2 = (const float*)d_in[18];
    const float* bc2 = (const float*)d_in[19];
    float* out = (float*)d_out;

    // workspace layout (all segments 16B-aligned)
    __half* XSH = (__half*)d_ws;                     // [N,128] fp16 proj out
    __half* H16 = XSH + (size_t)NN * HID;            // [N,128] fp16 gather out
    float* asrc = (float*)(H16 + (size_t)NN * HID);  // [N,4]
    float* adst = asrc + (size_t)NN * 4;             // [N,4]
    float* ve1 = adst + (size_t)NN * 4;              // [32]
    float* ve2 = ve1 + 32;                           // [32]
    float* pooled = ve2 + 32;                        // [64,128]
    float* counts = pooled + 64 * HID;               // [64]
    unsigned* rec = (unsigned*)(counts + 64);        // [E,8] uints: 2x16B sub-records
    __half* wt1 = (__half*)(rec + (size_t)NE * 8);   // [128,KP1]
    __half* wt2 = wt1 + HID * KP1;                   // [128,KP2]
    int* deg = (int*)(wt2 + HID * KP2);              // [N]
    int* cursor = deg + NN;                          // [N]
    int* startv = cursor + NN;                       // [N]
    int* bsum = startv + NN;                         // [256]

    int gProj = (NN + 63) / 64;  // 1563
    int gE = (NE + 255) / 256;
    int gGat = (NN + 3) / 4;
    int nScanBlk = (NN + 1023) / 1024;  // 98
    int gWP = (HID * KP1 + HID * KP2 + 255) / 256;

    // ===== one-time prep =====
    hipMemsetAsync(deg, 0, (size_t)2 * NN * sizeof(int), stream);  // deg + cursor
    compute_ve2<<<1, 64, 0, stream>>>(We1, att_edge1, We2, att_edge2, ve1, ve2);
    w_prep<<<gWP, 256, 0, stream>>>(W1, W2, wt1, wt2);
    k_deg<<<gE, 256, 0, stream>>>(ei, deg);
    scan_local<<<nScanBlk, 256, 0, stream>>>(deg, startv, bsum);
    scan_bsum<<<1, 256, 0, stream>>>(bsum, nScanBlk);
    scan_add<<<(NN + 255) / 256, 256, 0, stream>>>(startv, bsum);
    k_scatter<<<gE, 256, 0, stream>>>(ei, startv, cursor, eattr, ve1, ve2, rec);

    // ===== layer 1 =====
    mfma_proj<false><<<gProj, 256, 0, stream>>>(x, wt1, att_src1, att_dst1, XSH, asrc, adst,
                                                IN_DIM, KP1, (long long)NN * IN_DIM - 1);
    gat_gather<<<gGat, 256, 0, stream>>>(startv, deg, rec, asrc, adst,
                                         XSH, b1, H16);  // H16 = h1 (fp16)

    // ===== layer 2 =====
    mfma_proj<true><<<gProj, 256, 0, stream>>>(H16, wt2, att_src2, att_dst2, XSH, asrc, adst,
                                               HID, KP2, (long long)NN * HID - 1);
    gat_gather<<<gGat, 256, 0, stream>>>(startv, deg, rec + 4, asrc, adst,
                                         XSH, b2, H16);  // H16 = h2 (fp16)

    // ===== pool + classify =====
    hipMemsetAsync(pooled, 0, (64 * HID + 64) * sizeof(float), stream);
    pool_kernel<<<(NN + POOL_CHUNK - 1) / POOL_CHUNK, 256, 0, stream>>>(H16, batch, pooled, counts);
    classifier<<<64, 64, 0, stream>>>(pooled, counts, Wc1, bc1, Wc2, bc2, out);
}

// Round 27
// 442.046 us; speedup vs baseline: 1.2684x; 1.1232x over previous
//
#include <hip/hip_runtime.h>
#include <hip/hip_fp16.h>

#define NN 100000
#define NE 1600000
#define HID 128
#define HEADS 4
#define CH 32
#define IN_DIM 257
#define CHK 64   // edges per LDS chunk in gather
#define KP1 288  // padded K for layer-1 wt16 (9 chunks of 32; zeros past 257)
#define KP2 128

typedef float f32x4 __attribute__((ext_vector_type(4)));
typedef _Float16 h8 __attribute__((ext_vector_type(8)));
typedef unsigned u4v __attribute__((ext_vector_type(4)));

__device__ __forceinline__ __half2 u2h2(unsigned u) {
    union { unsigned u; __half2 h; } cv;
    cv.u = u;
    return cv.h;
}

// ==================== MFMA projection + fused attention scalars ====================
template <bool XHALF>
__global__ __launch_bounds__(256, 4) void mfma_proj(const void* __restrict__ Xin,
                                                    const __half* __restrict__ wt16,
                                                    const float* __restrict__ att_src,
                                                    const float* __restrict__ att_dst,
                                                    __half* __restrict__ XSH,
                                                    float* __restrict__ asrc,
                                                    float* __restrict__ adst,
                                                    int K, int KP, long long maxx) {
    __shared__ __half xt[2][64][40];
    __shared__ __half wtile[2][128][40];
    int tid = threadIdx.x;
    int lane = tid & 63;
    int wv = tid >> 6;
    int block0 = blockIdx.x * 64;
    int nchunk = (K + 31) >> 5;

    int sn = tid >> 2;        // node 0..63
    int skb = (tid & 3) * 8;  // k sub-block
    int wn = tid >> 1;        // w row 0..127
    int woff = (tid & 1) * 16;

    f32x4 acc[8];
#pragma unroll
    for (int i = 0; i < 8; ++i) acc[i] = (f32x4){0.f, 0.f, 0.f, 0.f};

    float xr[8];
    uint4 xrh;
    uint4 wr0, wr1;

    auto loadX = [&](int k0) {
        if (XHALF) {
            const __half* Xh = (const __half*)Xin;
            long long a = (long long)(block0 + sn) * K + k0 + skb;
            if (a > maxx - 7) a = maxx - 7;
            xrh = *(const uint4*)&Xh[a];
        } else {
            const float* Xf = (const float*)Xin;
#pragma unroll
            for (int j = 0; j < 8; ++j) {
                long long a = (long long)(block0 + sn) * K + k0 + skb + j;
                if (a > maxx) a = maxx;
                xr[j] = Xf[a];
            }
        }
    };
    auto writeX = [&](int buf) {
        if (XHALF) {
            *(uint4*)&xt[buf][sn][skb] = xrh;
        } else {
            __half2 p0 = __floats2half2_rn(xr[0], xr[1]);
            __half2 p1 = __floats2half2_rn(xr[2], xr[3]);
            __half2 p2 = __floats2half2_rn(xr[4], xr[5]);
            __half2 p3 = __floats2half2_rn(xr[6], xr[7]);
            uint4 w;
            w.x = *(unsigned*)&p0; w.y = *(unsigned*)&p1;
            w.z = *(unsigned*)&p2; w.w = *(unsigned*)&p3;
            *(uint4*)&xt[buf][sn][skb] = w;
        }
    };
    auto loadW = [&](int k0) {
        const __half* src = &wt16[(long long)wn * KP + k0 + woff];
        wr0 = *(const uint4*)src;
        wr1 = *(const uint4*)(src + 8);
    };
    auto writeW = [&](int buf) {
        *(uint4*)&wtile[buf][wn][woff] = wr0;
        *(uint4*)&wtile[buf][wn][woff + 8] = wr1;
    };

    // prologue
    loadX(0);
    loadW(0);
    asm volatile("s_waitcnt vmcnt(0)" ::: "memory");
    writeX(0);
    writeW(0);
    __syncthreads();

    int m0 = wv * 16;
    int li = lane & 15;
    int kg = (lane >> 4) * 8;

    for (int c = 0; c < nchunk; ++c) {
        int cur = c & 1;
        bool more = (c + 1 < nchunk);
        if (more) { loadX((c + 1) * 32); loadW((c + 1) * 32); }
        uint4 av = *(const uint4*)&xt[cur][m0 + li][kg];
        h8 a = *(h8*)&av;
#pragma unroll
        for (int nt = 0; nt < 8; ++nt) {
            uint4 bv = *(const uint4*)&wtile[cur][nt * 16 + li][kg];
            h8 b = *(h8*)&bv;
            acc[nt] = __builtin_amdgcn_mfma_f32_16x16x32_f16(a, b, acc[nt], 0, 0, 0);
        }
        if (more) {
            asm volatile("s_waitcnt vmcnt(0)" ::: "memory");
            writeX(cur ^ 1);
            writeW(cur ^ 1);
        }
        __syncthreads();
    }

    // epilogue: lane holds D[node=(lane>>4)*4+r][col=nt*16+li] = acc[nt][r].
    float as_[8], ad_[8];
#pragma unroll
    for (int nt = 0; nt < 8; ++nt) {
        as_[nt] = att_src[nt * 16 + li];
        ad_[nt] = att_dst[nt * 16 + li];
    }
    int rbase = (lane >> 4) * 4;
#pragma unroll
    for (int r = 0; r < 4; ++r) {
        int node = block0 + m0 + rbase + r;
        bool ok = node < NN;
        if (ok) {
#pragma unroll
            for (int nt = 0; nt < 8; ++nt)
                XSH[(size_t)node * HID + nt * 16 + li] = __float2half(acc[nt][r]);
        }
#pragma unroll
        for (int h = 0; h < 4; ++h) {
            float s = acc[2 * h][r] * as_[2 * h] + acc[2 * h + 1][r] * as_[2 * h + 1];
            float d = acc[2 * h][r] * ad_[2 * h] + acc[2 * h + 1][r] * ad_[2 * h + 1];
            s += __shfl_xor(s, 1); d += __shfl_xor(d, 1);
            s += __shfl_xor(s, 2); d += __shfl_xor(d, 2);
            s += __shfl_xor(s, 4); d += __shfl_xor(d, 4);
            s += __shfl_xor(s, 8); d += __shfl_xor(d, 8);
            if (ok && li == 0) {
                asrc[node * 4 + h] = s;
                adst[node * 4 + h] = d;
            }
        }
    }
}

// ---- W prep: wt16[n][k] = fp16(W[k][n]), zero-padded past K ----
__global__ __launch_bounds__(256) void w_prep(const float* __restrict__ W1,
                                              const float* __restrict__ W2,
                                              __half* __restrict__ wt1,
                                              __half* __restrict__ wt2) {
    int i = blockIdx.x * 256 + threadIdx.x;
    const int tot1 = HID * KP1;
    const int tot2 = HID * KP2;
    if (i < tot1) {
        int n = i / KP1, k = i % KP1;
        wt1[i] = (k < IN_DIM) ? __float2half(W1[(size_t)k * HID + n]) : __float2half(0.f);
    } else if (i < tot1 + tot2) {
        int i2 = i - tot1;
        int n = i2 >> 7, k = i2 & 127;
        wt2[i2] = __float2half(W2[(size_t)k * HID + n]);
    }
}

// ---- ve[d,h] = sum_c We[d, h*CH+c] * att_edge[h,c]  (8x4), both layers at once ----
__global__ void compute_ve2(const float* __restrict__ We1,
                            const float* __restrict__ ae1,
                            const float* __restrict__ We2,
                            const float* __restrict__ ae2,
                            float* __restrict__ ve1,
                            float* __restrict__ ve2) {
    int i = threadIdx.x;
    if (i >= 64) return;
    const float* We = (i < 32) ? We1 : We2;
    const float* ae = (i < 32) ? ae1 : ae2;
    float* ve = (i < 32) ? ve1 : ve2;
    int j = i & 31;
    int d = j >> 2, h = j & 3;
    float s = 0.f;
    for (int c = 0; c < CH; ++c) s += We[d * HID + h * CH + c] * ae[h * CH + c];
    ve[j] = s;
}

// ==================== CSR build ====================
__global__ __launch_bounds__(256) void k_deg(const int* __restrict__ ei, int* __restrict__ deg) {
    int e = blockIdx.x * 256 + threadIdx.x;
    if (e < NE) atomicAdd(&deg[ei[NE + e]], 1);
}

__global__ __launch_bounds__(256) void scan_local(const int* __restrict__ deg,
                                                  int* __restrict__ startv,
                                                  int* __restrict__ bsum) {
    __shared__ int sh[256];
    int t = threadIdx.x;
    int base = blockIdx.x * 1024 + t * 4;
    int v0 = 0, v1 = 0, v2 = 0, v3 = 0;
    if (base + 0 < NN) v0 = deg[base + 0];
    if (base + 1 < NN) v1 = deg[base + 1];
    if (base + 2 < NN) v2 = deg[base + 2];
    if (base + 3 < NN) v3 = deg[base + 3];
    int s1 = v0 + v1, s2 = s1 + v2, s3 = s2 + v3;
    sh[t] = s3;
    __syncthreads();
    for (int off = 1; off < 256; off <<= 1) {
        int x = (t >= off) ? sh[t - off] : 0;
        __syncthreads();
        sh[t] += x;
        __syncthreads();
    }
    int thOff = sh[t] - s3;  // exclusive
    if (base + 0 < NN) startv[base + 0] = thOff;
    if (base + 1 < NN) startv[base + 1] = thOff + v0;
    if (base + 2 < NN) startv[base + 2] = thOff + s1;
    if (base + 3 < NN) startv[base + 3] = thOff + s2;
    if (t == 255) bsum[blockIdx.x] = sh[255];
}

__global__ __launch_bounds__(256) void scan_bsum(int* __restrict__ bsum, int nb) {
    __shared__ int sh[256];
    int t = threadIdx.x;
    int v = (t < nb) ? bsum[t] : 0;
    sh[t] = v;
    __syncthreads();
    for (int off = 1; off < 256; off <<= 1) {
        int x = (t >= off) ? sh[t - off] : 0;
        __syncthreads();
        sh[t] += x;
        __syncthreads();
    }
    if (t < nb) bsum[t] = sh[t] - v;  // exclusive
}

__global__ __launch_bounds__(256) void scan_add(int* __restrict__ startv,
                                                const int* __restrict__ bsum) {
    int i = blockIdx.x * 256 + threadIdx.x;
    if (i < NN) startv[i] += bsum[i >> 10];
}

// scatter: per edge, ONE 32B record = two self-contained 16B sub-records
// {src, ae_fp16[4], pad} (one per layer) -> single random line touch per edge.
__global__ __launch_bounds__(256) void k_scatter(const int* __restrict__ ei,
                                                 const int* __restrict__ startv,
                                                 int* __restrict__ cursor,
                                                 const float* __restrict__ eattr,
                                                 const float* __restrict__ ve1,
                                                 const float* __restrict__ ve2,
                                                 unsigned* __restrict__ rec) {
    __shared__ float v1[32], v2[32];
    if (threadIdx.x < 32) v1[threadIdx.x] = ve1[threadIdx.x];
    else if (threadIdx.x < 64) v2[threadIdx.x - 32] = ve2[threadIdx.x - 32];
    __syncthreads();
    int e = blockIdx.x * 256 + threadIdx.x;
    if (e >= NE) return;
    int d = ei[NE + e];
    int src = ei[e];
    float4 e0 = *(const float4*)&eattr[(size_t)e * 8];
    float4 e1 = *(const float4*)&eattr[(size_t)e * 8 + 4];
    float eav[8] = {e0.x, e0.y, e0.z, e0.w, e1.x, e1.y, e1.z, e1.w};
    float a1[4], a2[4];
#pragma unroll
    for (int hh = 0; hh < 4; ++hh) {
        float s1 = 0.f, s2 = 0.f;
#pragma unroll
        for (int dd = 0; dd < 8; ++dd) {
            s1 += eav[dd] * v1[dd * 4 + hh];
            s2 += eav[dd] * v2[dd * 4 + hh];
        }
        a1[hh] = s1;
        a2[hh] = s2;
    }
    __half2 a1lo = __floats2half2_rn(a1[0], a1[1]);
    __half2 a1hi = __floats2half2_rn(a1[2], a1[3]);
    __half2 a2lo = __floats2half2_rn(a2[0], a2[1]);
    __half2 a2hi = __floats2half2_rn(a2[2], a2[3]);
    int pos = startv[d] + atomicAdd(&cursor[d], 1);
    uint4 r0, r1;
    r0.x = (unsigned)src; r0.y = *(unsigned*)&a1lo; r0.z = *(unsigned*)&a1hi; r0.w = 0;
    r1.x = (unsigned)src; r1.y = *(unsigned*)&a2lo; r1.z = *(unsigned*)&a2hi; r1.w = 0;
    *(uint4*)&rec[(size_t)pos * 8] = r0;
    *(uint4*)&rec[(size_t)pos * 8 + 4] = r1;
}

// ==================== fused gather: softmax (no-max) + aggregate + bias + relu ====
__global__ __launch_bounds__(256) void gat_gather(const int* __restrict__ startv,
                                                  const int* __restrict__ deg,
                                                  const unsigned* __restrict__ recL,  // rec + layer*4
                                                  const float* __restrict__ asrc,
                                                  const float* __restrict__ adst,
                                                  const __half* __restrict__ XSH,
                                                  const float* __restrict__ bias,
                                                  __half* __restrict__ OUT) {
    __shared__ float s_p[4][CHK * 4];
    __shared__ int s_src[4][CHK];
    int w = threadIdx.x >> 6;
    int wid = blockIdx.x * 4 + w;
    if (wid >= NN) return;
    int lane = threadIdx.x & 63;
    int s0 = startv[wid];
    int dg = deg[wid];
    float4 ad4 = *(const float4*)&adst[wid * 4];
    int h = lane >> 4;
    int c0 = lane * 2;

    float denom = 0.f, acc0 = 0.f, acc1 = 0.f;

    for (int cb = 0; cb < dg; cb += CHK) {
        int cnt = min(CHK, dg - cb);
        // stage: one 16B record per edge (wave-synchronous)
        for (int i = lane; i < cnt; i += 64) {
            int pos = s0 + cb + i;
            u4v rv = __builtin_nontemporal_load((const u4v*)&recL[(size_t)pos * 8]);
            int s = (int)rv.x;
            s_src[w][i] = s;
            float2 ae01 = __half22float2(u2h2(rv.y));
            float2 ae23 = __half22float2(u2h2(rv.z));
            float4 as4 = *(const float4*)&asrc[s * 4];
            float a0 = as4.x + ad4.x + ae01.x;
            float a1 = as4.y + ad4.y + ae01.y;
            float a2 = as4.z + ad4.z + ae23.x;
            float a3 = as4.w + ad4.w + ae23.y;
            a0 = (a0 > 0.f) ? a0 : 0.2f * a0;
            a1 = (a1 > 0.f) ? a1 : 0.2f * a1;
            a2 = (a2 > 0.f) ? a2 : 0.2f * a2;
            a3 = (a3 > 0.f) ? a3 : 0.2f * a3;
            *(float4*)&s_p[w][i * 4] =
                make_float4(__expf(a0), __expf(a1), __expf(a2), __expf(a3));
        }
        // accumulate sweep, 8 XS gathers in flight
        int j = 0;
        for (; j + 7 < cnt; j += 8) {
            int sv[8];
            float pv[8];
            __half2 xv[8];
#pragma unroll
            for (int q = 0; q < 8; ++q) {
                sv[q] = s_src[w][j + q];
                pv[q] = s_p[w][(j + q) * 4 + h];
            }
#pragma unroll
            for (int q = 0; q < 8; ++q) xv[q] = *(const __half2*)&XSH[(size_t)sv[q] * HID + c0];
#pragma unroll
            for (int q = 0; q < 8; ++q) {
                float2 xf = __half22float2(xv[q]);
                denom += pv[q];
                acc0 += pv[q] * xf.x;
                acc1 += pv[q] * xf.y;
            }
        }
        for (; j < cnt; ++j) {
            int s = s_src[w][j];
            float p = s_p[w][j * 4 + h];
            float2 xf = __half22float2(*(const __half2*)&XSH[(size_t)s * HID + c0]);
            denom += p;
            acc0 += p * xf.x;
            acc1 += p * xf.y;
        }
    }
    float inv_ = 1.f / (denom + 1e-16f);
    float2 bv = *(const float2*)&bias[c0];
    float o0 = fmaxf(acc0 * inv_ + bv.x, 0.f);
    float o1 = fmaxf(acc1 * inv_ + bv.y, 0.f);
    *(__half2*)&OUT[(size_t)wid * HID + c0] = __floats2half2_rn(o0, o1);
}

// ==================== pooling: register accumulation over sorted batch ====
// Wave w of each block strides nodes (n0+w, n0+w+4, ...) in a 128-node stripe;
// lane covers channel-pair c2. One contiguous 256B row read per node (coalesced).
// Accumulate in registers while graph id (wave-uniform) unchanged; flush via
// global atomicAdd only at graph boundaries / stripe end (~3K flushes total).
#define POOL_NODES 128
__global__ __launch_bounds__(256) void pool_kernel(const __half* __restrict__ H,
                                                   const int* __restrict__ batch,
                                                   float* __restrict__ pooled,
                                                   float* __restrict__ counts) {
    int tid = threadIdx.x;
    int lane = tid & 63;
    int wvi = tid >> 6;  // 0..3
    int c2 = lane * 2;
    int n0 = blockIdx.x * POOL_NODES;
    int nend = min(n0 + POOL_NODES, NN);
    float a0 = 0.f, a1 = 0.f, cnt = 0.f;
    int gcur = -1;
    for (int n = n0 + wvi; n < nend; n += 4) {
        int g = batch[n];
        if (g != gcur) {
            if (gcur >= 0) {
                atomicAdd(&pooled[gcur * HID + c2], a0);
                atomicAdd(&pooled[gcur * HID + c2 + 1], a1);
                if (lane == 0) atomicAdd(&counts[gcur], cnt);
            }
            gcur = g;
            a0 = a1 = cnt = 0.f;
        }
        float2 hv = __half22float2(*(const __half2*)&H[(size_t)n * HID + c2]);
        a0 += hv.x;
        a1 += hv.y;
        cnt += 1.f;
    }
    if (gcur >= 0) {
        atomicAdd(&pooled[gcur * HID + c2], a0);
        atomicAdd(&pooled[gcur * HID + c2 + 1], a1);
        if (lane == 0) atomicAdd(&counts[gcur], cnt);
    }
}

// ==================== classifier ====================
__global__ __launch_bounds__(64) void classifier(const float* __restrict__ pooled,
                                                 const float* __restrict__ counts,
                                                 const float* __restrict__ Wc1,
                                                 const float* __restrict__ bc1,
                                                 const float* __restrict__ Wc2,
                                                 const float* __restrict__ bc2,
                                                 float* __restrict__ out) {
    __shared__ float pl[HID];
    __shared__ float z[64];
    int g = blockIdx.x, t = threadIdx.x;
    float inv = 1.f / fmaxf(counts[g], 1.f);
    pl[t] = pooled[g * HID + t] * inv;
    pl[t + 64] = pooled[g * HID + 64 + t] * inv;
    __syncthreads();
    float a = bc1[t];
    for (int k = 0; k < HID; ++k) a += pl[k] * Wc1[k * 64 + t];
    z[t] = fmaxf(a, 0.f);
    __syncthreads();
    if (t < 2) {
        float o = bc2[t];
        for (int j = 0; j < 64; ++j) o += z[j] * Wc2[j * 2 + t];
        out[g * 2 + t] = o;
    }
}

extern "C" void kernel_launch(void* const* d_in, const int* in_sizes, int n_in,
                              void* d_out, int out_size, void* d_ws, size_t ws_size,
                              hipStream_t stream) {
    const float* x = (const float*)d_in[0];
    const int* ei = (const int*)d_in[1];
    const float* eattr = (const float*)d_in[2];
    const int* batch = (const int*)d_in[3];
    const float* W1 = (const float*)d_in[4];
    const float* att_src1 = (const float*)d_in[5];
    const float* att_dst1 = (const float*)d_in[6];
    const float* We1 = (const float*)d_in[7];
    const float* att_edge1 = (const float*)d_in[8];
    const float* b1 = (const float*)d_in[9];
    const float* W2 = (const float*)d_in[10];
    const float* att_src2 = (const float*)d_in[11];
    const float* att_dst2 = (const float*)d_in[12];
    const float* We2 = (const float*)d_in[13];
    const float* att_edge2 = (const float*)d_in[14];
    const float* b2 = (const float*)d_in[15];
    const float* Wc1 = (const float*)d_in[16];
    const float* bc1 = (const float*)d_in[17];
    const float* Wc2 = (const float*)d_in[18];
    const float* bc2 = (const float*)d_in[19];
    float* out = (float*)d_out;

    // workspace layout (all segments 16B-aligned)
    __half* XSH = (__half*)d_ws;                     // [N,128] fp16 proj out
    __half* H16 = XSH + (size_t)NN * HID;            // [N,128] fp16 gather out
    float* asrc = (float*)(H16 + (size_t)NN * HID);  // [N,4]
    float* adst = asrc + (size_t)NN * 4;             // [N,4]
    float* ve1 = adst + (size_t)NN * 4;              // [32]
    float* ve2 = ve1 + 32;                           // [32]
    float* pooled = ve2 + 32;                        // [64,128]
    float* counts = pooled + 64 * HID;               // [64]
    unsigned* rec = (unsigned*)(counts + 64);        // [E,8] uints: 2x16B sub-records
    __half* wt1 = (__half*)(rec + (size_t)NE * 8);   // [128,KP1]
    __half* wt2 = wt1 + HID * KP1;                   // [128,KP2]
    int* deg = (int*)(wt2 + HID * KP2);              // [N]
    int* cursor = deg + NN;                          // [N]
    int* startv = cursor + NN;                       // [N]
    int* bsum = startv + NN;                         // [256]

    int gProj = (NN + 63) / 64;  // 1563
    int gE = (NE + 255) / 256;
    int gGat = (NN + 3) / 4;
    int nScanBlk = (NN + 1023) / 1024;  // 98
    int gWP = (HID * KP1 + HID * KP2 + 255) / 256;

    // ===== one-time prep =====
    hipMemsetAsync(deg, 0, (size_t)2 * NN * sizeof(int), stream);  // deg + cursor
    compute_ve2<<<1, 64, 0, stream>>>(We1, att_edge1, We2, att_edge2, ve1, ve2);
    w_prep<<<gWP, 256, 0, stream>>>(W1, W2, wt1, wt2);
    k_deg<<<gE, 256, 0, stream>>>(ei, deg);
    scan_local<<<nScanBlk, 256, 0, stream>>>(deg, startv, bsum);
    scan_bsum<<<1, 256, 0, stream>>>(bsum, nScanBlk);
    scan_add<<<(NN + 255) / 256, 256, 0, stream>>>(startv, bsum);
    k_scatter<<<gE, 256, 0, stream>>>(ei, startv, cursor, eattr, ve1, ve2, rec);

    // ===== layer 1 =====
    mfma_proj<false><<<gProj, 256, 0, stream>>>(x, wt1, att_src1, att_dst1, XSH, asrc, adst,
                                                IN_DIM, KP1, (long long)NN * IN_DIM - 1);
    gat_gather<<<gGat, 256, 0, stream>>>(startv, deg, rec, asrc, adst,
                                         XSH, b1, H16);  // H16 = h1 (fp16)

    // ===== layer 2 =====
    mfma_proj<true><<<gProj, 256, 0, stream>>>(H16, wt2, att_src2, att_dst2, XSH, asrc, adst,
                                               HID, KP2, (long long)NN * HID - 1);
    gat_gather<<<gGat, 256, 0, stream>>>(startv, deg, rec + 4, asrc, adst,
                                         XSH, b2, H16);  // H16 = h2 (fp16)

    // ===== pool + classify =====
    hipMemsetAsync(pooled, 0, (64 * HID + 64) * sizeof(float), stream);
    pool_kernel<<<(NN + POOL_NODES - 1) / POOL_NODES, 256, 0, stream>>>(H16, batch, pooled, counts);
    classifier<<<64, 64, 0, stream>>>(pooled, counts, Wc1, bc1, Wc2, bc2, out);
}